// Round 4
// baseline (579.449 us; speedup 1.0000x reference)
//
#include <hip/hip_runtime.h>
#include <math.h>

#define N_NODES 8192
#define N_COMM 16
#define DIMS 64
#define MROWS 4                    // ricci rows per block
#define ITERS (N_NODES / 256)      // 32 j-iterations, one j per thread per iter

typedef float v4f __attribute__((ext_vector_type(4)));

// ---------------------------------------------------------------------------
// Kernel 1: pi[i,k] = softmax_k( sqrt(d_euc^2 + d_lor^2 + d_sph^2) )
// One lane per (node, k): t = i*16 + k. 16-lane softmax via shfl_xor(1,2,4,8).
// Writes pi row-major (for epilogue fold) AND transposed piT (for k_main).
// ---------------------------------------------------------------------------
__global__ __launch_bounds__(256) void k_pi(
    const float* __restrict__ node,   // (3, 8192, 64)
    const float* __restrict__ comm,   // (16, 64)
    float* __restrict__ pi,           // (8192, 16)
    float* __restrict__ piT)          // (16, 8192)
{
  const int t = blockIdx.x * blockDim.x + threadIdx.x;  // 0..131071
  const int i = t >> 4;
  const int k = t & 15;

  const float* xe = node + (size_t)i * DIMS;                  // Euclidean (curv 0)
  const float* xl = xe + (size_t)N_NODES * DIMS;              // Lorentz  (curv -1)
  const float* xs = xl + (size_t)N_NODES * DIMS;              // Sphere   (curv +1)
  const float* c  = comm + k * DIMS;

  float de = 0.f, il = 0.f, isp = 0.f;
#pragma unroll
  for (int d = 0; d < DIMS; d += 4) {
    v4f a  = *(const v4f*)(xe + d);
    v4f b  = *(const v4f*)(xl + d);
    v4f e  = *(const v4f*)(xs + d);
    v4f cv = *(const v4f*)(c + d);
    v4f df = a - cv;
    de  += df.x * df.x + df.y * df.y + df.z * df.z + df.w * df.w;
    il  += b.x * cv.x + b.y * cv.y + b.z * cv.z + b.w * cv.w;
    isp += e.x * cv.x + e.y * cv.y + e.z * cv.z + e.w * cv.w;
  }

  // Lorentz (kk = 1): lip = <x,c> - 2*x0*c0 ; d = arccosh(max(-lip, 1+eps))
  float lip = il - 2.0f * xl[0] * c[0];
  float arg = fmaxf(-lip, 1.0f + 1e-7f);
  float d1  = acoshf(arg);
  // Sphere: d = arccos(clip(<x,c>, -1+eps, 1-eps))
  float cs = fminf(fmaxf(isp, -1.0f + 1e-7f), 1.0f - 1e-7f);
  float d2 = acosf(cs);

  float dn = sqrtf(de + d1 * d1 + d2 * d2);

  // softmax over the 16 lanes sharing this node (lane mask bits 0..3)
  float m = dn;
#pragma unroll
  for (int off = 1; off < 16; off <<= 1) m = fmaxf(m, __shfl_xor(m, off));
  float ex = expf(dn - m);
  float ss = ex;
#pragma unroll
  for (int off = 1; off < 16; off <<= 1) ss += __shfl_xor(ss, off);

  float v = ex / ss;
  pi[t] = v;                     // coalesced
  piT[k * N_NODES + i] = v;      // scattered, but tiny (one store/thread)
}

// ---------------------------------------------------------------------------
// Kernel 2: single streaming pass over ricci, ALL loads dense (lane-stride 4B).
// Thread owns one j per iteration. Per iter: 16 scalar piT loads + 4 scalar
// ricci loads (each 256 B/wave-instr), 64 FMAs into acc[4][16].
// Manual 2-stage ping-pong prefetch hides one full iteration of load latency.
//   intra += sum_{r,k} pi[i0+r,k] * acc[r][k]
//   inter += sum_{r,k} acc[r][k]       (s = pi.sum(1) absorbed into col-sums)
// ---------------------------------------------------------------------------
__global__ __launch_bounds__(256, 4) void k_main(
    const float* __restrict__ ricci,   // (8192, 8192)
    const float* __restrict__ pi,      // (8192, 16) row-major
    const float* __restrict__ piT,     // (16, 8192)
    double* __restrict__ accum)        // [0]=intra_sum, [1]=inter_sum
{
  const int i0  = blockIdx.x * MROWS;       // 2048 blocks
  const int tid = threadIdx.x;
  const float* __restrict__ rbase = ricci + (size_t)i0 * N_NODES;

  float acc[MROWS][N_COMM] = {};            // 64 VGPRs
  float p[2][N_COMM], rv[2][MROWS];

  // prologue: loads for it = 0
#pragma unroll
  for (int k = 0; k < N_COMM; ++k) p[0][k] = piT[k * N_NODES + tid];
#pragma unroll
  for (int r = 0; r < MROWS; ++r) rv[0][r] = rbase[(size_t)r * N_NODES + tid];

#pragma unroll
  for (int it = 0; it < ITERS; ++it) {
    const int cur = it & 1, nxt = cur ^ 1;
    if (it + 1 < ITERS) {                   // constant after full unroll
      const int jn = (it + 1) * 256 + tid;
#pragma unroll
      for (int k = 0; k < N_COMM; ++k) p[nxt][k] = piT[k * N_NODES + jn];
#pragma unroll
      for (int r = 0; r < MROWS; ++r) rv[nxt][r] = rbase[(size_t)r * N_NODES + jn];
    }
#pragma unroll
    for (int r = 0; r < MROWS; ++r)
#pragma unroll
      for (int k = 0; k < N_COMM; ++k)
        acc[r][k] += rv[cur][r] * p[cur][k];
  }

  // per-thread epilogue: fold acc with pi rows i0..i0+3 (broadcast loads)
  float fintra = 0.f, finter = 0.f;
#pragma unroll
  for (int r = 0; r < MROWS; ++r) {
#pragma unroll
    for (int k = 0; k < N_COMM; ++k) {
      fintra += pi[(i0 + r) * N_COMM + k] * acc[r][k];
      finter += acc[r][k];
    }
  }

  // wave reduce (64 lanes) in double, then block reduce, 2 atomics/block
  double di = (double)fintra, dn = (double)finter;
#pragma unroll
  for (int off = 32; off > 0; off >>= 1) {
    di += __shfl_down(di, off);
    dn += __shfl_down(dn, off);
  }
  __shared__ double red[8];
  const int w = tid >> 6;
  if ((tid & 63) == 0) { red[w] = di; red[4 + w] = dn; }
  __syncthreads();
  if (tid == 0) {
    atomicAdd(&accum[0], red[0] + red[1] + red[2] + red[3]);
    atomicAdd(&accum[1], red[4] + red[5] + red[6] + red[7]);
  }
}

// ---------------------------------------------------------------------------
// Kernel 3: out = alpha * intra_sum/(K*N) - inter_sum/(K*K*N)
// ---------------------------------------------------------------------------
__global__ void k_final(const double* __restrict__ accum,
                        const float* __restrict__ alpha,
                        float* __restrict__ out)
{
  const double KN  = (double)N_COMM * (double)N_NODES;
  const double KKN = (double)N_COMM * (double)N_COMM * (double)N_NODES;
  out[0] = (float)((double)alpha[0] * (accum[0] / KN) - accum[1] / KKN);
}

extern "C" void kernel_launch(void* const* d_in, const int* in_sizes, int n_in,
                              void* d_out, int out_size, void* d_ws, size_t ws_size,
                              hipStream_t stream) {
  (void)in_sizes; (void)n_in; (void)out_size; (void)ws_size;

  const float* node  = (const float*)d_in[0];  // (3, 8192, 64) fp32
  const float* comm  = (const float*)d_in[1];  // (16, 64) fp32
  const float* ricci = (const float*)d_in[2];  // (8192, 8192) fp32
  const float* alpha = (const float*)d_in[3];  // scalar fp32
  float* out = (float*)d_out;

  double* accum = (double*)d_ws;                         // 2 doubles @ 0
  float*  pi    = (float*)((char*)d_ws + 64);            // 512 KB
  float*  piT   = (float*)((char*)d_ws + 64 + 524288);   // 512 KB

  // ws is re-poisoned to 0xAA before every launch: zero the accumulators.
  (void)hipMemsetAsync(d_ws, 0, 64, stream);

  hipLaunchKernelGGL(k_pi,   dim3((N_NODES * N_COMM) / 256), dim3(256), 0, stream,
                     node, comm, pi, piT);
  hipLaunchKernelGGL(k_main, dim3(N_NODES / MROWS), dim3(256), 0, stream,
                     ricci, pi, piT, accum);
  hipLaunchKernelGGL(k_final, dim3(1), dim3(1), 0, stream, accum, alpha, out);
}

// Round 5
// 418.069 us; speedup vs baseline: 1.3860x; 1.3860x over previous
//
#include <hip/hip_runtime.h>
#include <math.h>

#define N_NODES 8192
#define N_COMM 16
#define DIMS 64
#define MROWS 4                    // ricci rows per block
#define ITERS (N_NODES / 256)      // 32 j-iterations, one j per thread per iter

typedef float v4f __attribute__((ext_vector_type(4)));

// ---------------------------------------------------------------------------
// Kernel 1: pi[i,k] = softmax_k( sqrt(d_euc^2 + d_lor^2 + d_sph^2) )
// One lane per (node, k): t = i*16 + k. 16-lane softmax via shfl_xor(1,2,4,8).
// Writes pi row-major (for epilogue fold) AND transposed piT (for k_main).
// ---------------------------------------------------------------------------
__global__ __launch_bounds__(256) void k_pi(
    const float* __restrict__ node,   // (3, 8192, 64)
    const float* __restrict__ comm,   // (16, 64)
    float* __restrict__ pi,           // (8192, 16)
    float* __restrict__ piT)          // (16, 8192)
{
  const int t = blockIdx.x * blockDim.x + threadIdx.x;  // 0..131071
  const int i = t >> 4;
  const int k = t & 15;

  const float* xe = node + (size_t)i * DIMS;                  // Euclidean (curv 0)
  const float* xl = xe + (size_t)N_NODES * DIMS;              // Lorentz  (curv -1)
  const float* xs = xl + (size_t)N_NODES * DIMS;              // Sphere   (curv +1)
  const float* c  = comm + k * DIMS;

  float de = 0.f, il = 0.f, isp = 0.f;
#pragma unroll
  for (int d = 0; d < DIMS; d += 4) {
    v4f a  = *(const v4f*)(xe + d);
    v4f b  = *(const v4f*)(xl + d);
    v4f e  = *(const v4f*)(xs + d);
    v4f cv = *(const v4f*)(c + d);
    v4f df = a - cv;
    de  += df.x * df.x + df.y * df.y + df.z * df.z + df.w * df.w;
    il  += b.x * cv.x + b.y * cv.y + b.z * cv.z + b.w * cv.w;
    isp += e.x * cv.x + e.y * cv.y + e.z * cv.z + e.w * cv.w;
  }

  // Lorentz (kk = 1): lip = <x,c> - 2*x0*c0 ; d = arccosh(max(-lip, 1+eps))
  float lip = il - 2.0f * xl[0] * c[0];
  float arg = fmaxf(-lip, 1.0f + 1e-7f);
  float d1  = acoshf(arg);
  // Sphere: d = arccos(clip(<x,c>, -1+eps, 1-eps))
  float cs = fminf(fmaxf(isp, -1.0f + 1e-7f), 1.0f - 1e-7f);
  float d2 = acosf(cs);

  float dn = sqrtf(de + d1 * d1 + d2 * d2);

  // softmax over the 16 lanes sharing this node (lane mask bits 0..3)
  float m = dn;
#pragma unroll
  for (int off = 1; off < 16; off <<= 1) m = fmaxf(m, __shfl_xor(m, off));
  float ex = expf(dn - m);
  float ss = ex;
#pragma unroll
  for (int off = 1; off < 16; off <<= 1) ss += __shfl_xor(ss, off);

  float v = ex / ss;
  pi[t] = v;                     // coalesced
  piT[k * N_NODES + i] = v;      // scattered, but tiny (one store/thread)
}

// ---------------------------------------------------------------------------
// Kernel 2: single streaming pass over ricci, ALL loads dense (lane-stride 4B).
// Thread owns one j per iteration. Per iter: 16 scalar piT loads + 4 scalar
// ricci loads (each 256 B/wave-instr), 64 FMAs into acc[4][16].
// Manual 2-stage ping-pong prefetch hides one full iteration of load latency.
// NOTE: no min-waves launch-bounds arg — R4's (256,4) made the backend clamp
// VGPRs to 64 and spill acc[] to scratch (396 MB of scratch writes/dispatch).
//   intra += sum_{r,k} pi[i0+r,k] * acc[r][k]
//   inter += sum_{r,k} acc[r][k]       (s = pi.sum(1) absorbed into col-sums)
// ---------------------------------------------------------------------------
__global__ __launch_bounds__(256) void k_main(
    const float* __restrict__ ricci,   // (8192, 8192)
    const float* __restrict__ pi,      // (8192, 16) row-major
    const float* __restrict__ piT,     // (16, 8192)
    double* __restrict__ accum)        // [0]=intra_sum, [1]=inter_sum
{
  const int i0  = blockIdx.x * MROWS;       // 2048 blocks
  const int tid = threadIdx.x;
  const float* __restrict__ rbase = ricci + (size_t)i0 * N_NODES;

  float acc[MROWS][N_COMM] = {};            // 64 VGPRs
  float p[2][N_COMM], rv[2][MROWS];

  // prologue: loads for it = 0
#pragma unroll
  for (int k = 0; k < N_COMM; ++k) p[0][k] = piT[k * N_NODES + tid];
#pragma unroll
  for (int r = 0; r < MROWS; ++r) rv[0][r] = rbase[(size_t)r * N_NODES + tid];

#pragma unroll
  for (int it = 0; it < ITERS; ++it) {
    const int cur = it & 1, nxt = cur ^ 1;
    if (it + 1 < ITERS) {                   // constant after full unroll
      const int jn = (it + 1) * 256 + tid;
#pragma unroll
      for (int k = 0; k < N_COMM; ++k) p[nxt][k] = piT[k * N_NODES + jn];
#pragma unroll
      for (int r = 0; r < MROWS; ++r) rv[nxt][r] = rbase[(size_t)r * N_NODES + jn];
    }
#pragma unroll
    for (int r = 0; r < MROWS; ++r)
#pragma unroll
      for (int k = 0; k < N_COMM; ++k)
        acc[r][k] += rv[cur][r] * p[cur][k];
  }

  // per-thread epilogue: fold acc with pi rows i0..i0+3 (broadcast loads)
  float fintra = 0.f, finter = 0.f;
#pragma unroll
  for (int r = 0; r < MROWS; ++r) {
#pragma unroll
    for (int k = 0; k < N_COMM; ++k) {
      fintra += pi[(i0 + r) * N_COMM + k] * acc[r][k];
      finter += acc[r][k];
    }
  }

  // wave reduce (64 lanes) in double, then block reduce, 2 atomics/block
  double di = (double)fintra, dn = (double)finter;
#pragma unroll
  for (int off = 32; off > 0; off >>= 1) {
    di += __shfl_down(di, off);
    dn += __shfl_down(dn, off);
  }
  __shared__ double red[8];
  const int w = tid >> 6;
  if ((tid & 63) == 0) { red[w] = di; red[4 + w] = dn; }
  __syncthreads();
  if (tid == 0) {
    atomicAdd(&accum[0], red[0] + red[1] + red[2] + red[3]);
    atomicAdd(&accum[1], red[4] + red[5] + red[6] + red[7]);
  }
}

// ---------------------------------------------------------------------------
// Kernel 3: out = alpha * intra_sum/(K*N) - inter_sum/(K*K*N)
// ---------------------------------------------------------------------------
__global__ void k_final(const double* __restrict__ accum,
                        const float* __restrict__ alpha,
                        float* __restrict__ out)
{
  const double KN  = (double)N_COMM * (double)N_NODES;
  const double KKN = (double)N_COMM * (double)N_COMM * (double)N_NODES;
  out[0] = (float)((double)alpha[0] * (accum[0] / KN) - accum[1] / KKN);
}

extern "C" void kernel_launch(void* const* d_in, const int* in_sizes, int n_in,
                              void* d_out, int out_size, void* d_ws, size_t ws_size,
                              hipStream_t stream) {
  (void)in_sizes; (void)n_in; (void)out_size; (void)ws_size;

  const float* node  = (const float*)d_in[0];  // (3, 8192, 64) fp32
  const float* comm  = (const float*)d_in[1];  // (16, 64) fp32
  const float* ricci = (const float*)d_in[2];  // (8192, 8192) fp32
  const float* alpha = (const float*)d_in[3];  // scalar fp32
  float* out = (float*)d_out;

  double* accum = (double*)d_ws;                         // 2 doubles @ 0
  float*  pi    = (float*)((char*)d_ws + 64);            // 512 KB
  float*  piT   = (float*)((char*)d_ws + 64 + 524288);   // 512 KB

  // ws is re-poisoned to 0xAA before every launch: zero the accumulators.
  (void)hipMemsetAsync(d_ws, 0, 64, stream);

  hipLaunchKernelGGL(k_pi,   dim3((N_NODES * N_COMM) / 256), dim3(256), 0, stream,
                     node, comm, pi, piT);
  hipLaunchKernelGGL(k_main, dim3(N_NODES / MROWS), dim3(256), 0, stream,
                     ricci, pi, piT, accum);
  hipLaunchKernelGGL(k_final, dim3(1), dim3(1), 0, stream, accum, alpha, out);
}

// Round 6
// 406.356 us; speedup vs baseline: 1.4260x; 1.0288x over previous
//
#include <hip/hip_runtime.h>
#include <math.h>

#define N_NODES 8192
#define N_COMM 16
#define DIMS 64
#define MROWS 4                      // ricci rows per block
#define JQ 4                         // j-quad per thread
#define JPI (256 * JQ)               // 1024 j's per block-iteration
#define ITERS (N_NODES / JPI)        // 8 iterations, full j-range per block

typedef float v4f __attribute__((ext_vector_type(4)));

// ---------------------------------------------------------------------------
// Kernel 1: pi[i,k] = softmax_k( sqrt(d_euc^2 + d_lor^2 + d_sph^2) )
// One lane per (node, k): t = i*16 + k. 16-lane softmax via shfl_xor(1,2,4,8).
// Writes pi row-major (for epilogue fold) AND transposed piT (for k_main).
// ---------------------------------------------------------------------------
__global__ __launch_bounds__(256) void k_pi(
    const float* __restrict__ node,   // (3, 8192, 64)
    const float* __restrict__ comm,   // (16, 64)
    float* __restrict__ pi,           // (8192, 16)
    float* __restrict__ piT)          // (16, 8192)
{
  const int t = blockIdx.x * blockDim.x + threadIdx.x;  // 0..131071
  const int i = t >> 4;
  const int k = t & 15;

  const float* xe = node + (size_t)i * DIMS;                  // Euclidean (curv 0)
  const float* xl = xe + (size_t)N_NODES * DIMS;              // Lorentz  (curv -1)
  const float* xs = xl + (size_t)N_NODES * DIMS;              // Sphere   (curv +1)
  const float* c  = comm + k * DIMS;

  float de = 0.f, il = 0.f, isp = 0.f;
#pragma unroll
  for (int d = 0; d < DIMS; d += 4) {
    v4f a  = *(const v4f*)(xe + d);
    v4f b  = *(const v4f*)(xl + d);
    v4f e  = *(const v4f*)(xs + d);
    v4f cv = *(const v4f*)(c + d);
    v4f df = a - cv;
    de  += df.x * df.x + df.y * df.y + df.z * df.z + df.w * df.w;
    il  += b.x * cv.x + b.y * cv.y + b.z * cv.z + b.w * cv.w;
    isp += e.x * cv.x + e.y * cv.y + e.z * cv.z + e.w * cv.w;
  }

  // Lorentz (kk = 1): lip = <x,c> - 2*x0*c0 ; d = arccosh(max(-lip, 1+eps))
  float lip = il - 2.0f * xl[0] * c[0];
  float arg = fmaxf(-lip, 1.0f + 1e-7f);
  float d1  = acoshf(arg);
  // Sphere: d = arccos(clip(<x,c>, -1+eps, 1-eps))
  float cs = fminf(fmaxf(isp, -1.0f + 1e-7f), 1.0f - 1e-7f);
  float d2 = acosf(cs);

  float dn = sqrtf(de + d1 * d1 + d2 * d2);

  // softmax over the 16 lanes sharing this node (lane mask bits 0..3)
  float m = dn;
#pragma unroll
  for (int off = 1; off < 16; off <<= 1) m = fmaxf(m, __shfl_xor(m, off));
  float ex = expf(dn - m);
  float ss = ex;
#pragma unroll
  for (int off = 1; off < 16; off <<= 1) ss += __shfl_xor(ss, off);

  float v = ex / ss;
  pi[t] = v;                     // coalesced
  piT[k * N_NODES + i] = v;      // scattered, but tiny (one store/thread)
}

// ---------------------------------------------------------------------------
// Kernel 2: single streaming pass over ricci, quad-j per thread.
// All loads are dwordx4 at lane-stride 16 B (1 KB dense per wave-instr):
//   - rv[r]: ricci[i0+r][j..j+3]  (ping-pong prefetched, 4 KB in flight/wave)
//   - p[k] : piT[k][j..j+3]       (L2-resident, loaded per 4-k group)
//   acc[r][k] += dot4(rv[r], p[k])   -> 256 FMAs/iter, acc stays 64 scalars
//   intra += sum_{r,k} pi[i0+r,k]*acc[r][k] ; inter += sum_{r,k} acc[r][k]
// NO min-waves launch bound (R4: (256,4) clamped to 64 VGPR -> 396 MB spill).
// ---------------------------------------------------------------------------
__global__ __launch_bounds__(256) void k_main(
    const float* __restrict__ ricci,   // (8192, 8192)
    const float* __restrict__ pi,      // (8192, 16) row-major
    const float* __restrict__ piT,     // (16, 8192)
    double* __restrict__ accum)        // [0]=intra_sum, [1]=inter_sum
{
  const int i0  = blockIdx.x * MROWS;       // 2048 blocks
  const int tid = threadIdx.x;
  const float* __restrict__ rbase = ricci + (size_t)i0 * N_NODES;

  float acc[MROWS][N_COMM] = {};            // 64 VGPRs
  v4f rv[2][MROWS];                         // 32 VGPRs (ping-pong)

  // prologue: ricci quads for it = 0
  {
    const int j = tid * JQ;
#pragma unroll
    for (int r = 0; r < MROWS; ++r)
      rv[0][r] = *(const v4f*)(rbase + (size_t)r * N_NODES + j);
  }

#pragma unroll
  for (int it = 0; it < ITERS; ++it) {
    const int cur = it & 1, nxt = cur ^ 1;
    const int j = it * JPI + tid * JQ;

    if (it + 1 < ITERS) {                   // constant after full unroll
      const int jn = j + JPI;
#pragma unroll
      for (int r = 0; r < MROWS; ++r)
        rv[nxt][r] = *(const v4f*)(rbase + (size_t)r * N_NODES + jn);
    }

#pragma unroll
    for (int kg = 0; kg < N_COMM; kg += 4) {
      v4f p0 = *(const v4f*)(piT + (size_t)(kg + 0) * N_NODES + j);
      v4f p1 = *(const v4f*)(piT + (size_t)(kg + 1) * N_NODES + j);
      v4f p2 = *(const v4f*)(piT + (size_t)(kg + 2) * N_NODES + j);
      v4f p3 = *(const v4f*)(piT + (size_t)(kg + 3) * N_NODES + j);
#pragma unroll
      for (int r = 0; r < MROWS; ++r) {
        v4f rr = rv[cur][r];
        acc[r][kg + 0] += rr.x * p0.x + rr.y * p0.y + rr.z * p0.z + rr.w * p0.w;
        acc[r][kg + 1] += rr.x * p1.x + rr.y * p1.y + rr.z * p1.z + rr.w * p1.w;
        acc[r][kg + 2] += rr.x * p2.x + rr.y * p2.y + rr.z * p2.z + rr.w * p2.w;
        acc[r][kg + 3] += rr.x * p3.x + rr.y * p3.y + rr.z * p3.z + rr.w * p3.w;
      }
    }
  }

  // per-thread epilogue: fold acc with pi rows i0..i0+3 (broadcast loads)
  float fintra = 0.f, finter = 0.f;
#pragma unroll
  for (int r = 0; r < MROWS; ++r) {
#pragma unroll
    for (int k = 0; k < N_COMM; ++k) {
      fintra += pi[(i0 + r) * N_COMM + k] * acc[r][k];
      finter += acc[r][k];
    }
  }

  // wave reduce (64 lanes) in double, then block reduce, 2 atomics/block
  double di = (double)fintra, dn = (double)finter;
#pragma unroll
  for (int off = 32; off > 0; off >>= 1) {
    di += __shfl_down(di, off);
    dn += __shfl_down(dn, off);
  }
  __shared__ double red[8];
  const int w = tid >> 6;
  if ((tid & 63) == 0) { red[w] = di; red[4 + w] = dn; }
  __syncthreads();
  if (tid == 0) {
    atomicAdd(&accum[0], red[0] + red[1] + red[2] + red[3]);
    atomicAdd(&accum[1], red[4] + red[5] + red[6] + red[7]);
  }
}

// ---------------------------------------------------------------------------
// Kernel 3: out = alpha * intra_sum/(K*N) - inter_sum/(K*K*N)
// ---------------------------------------------------------------------------
__global__ void k_final(const double* __restrict__ accum,
                        const float* __restrict__ alpha,
                        float* __restrict__ out)
{
  const double KN  = (double)N_COMM * (double)N_NODES;
  const double KKN = (double)N_COMM * (double)N_COMM * (double)N_NODES;
  out[0] = (float)((double)alpha[0] * (accum[0] / KN) - accum[1] / KKN);
}

extern "C" void kernel_launch(void* const* d_in, const int* in_sizes, int n_in,
                              void* d_out, int out_size, void* d_ws, size_t ws_size,
                              hipStream_t stream) {
  (void)in_sizes; (void)n_in; (void)out_size; (void)ws_size;

  const float* node  = (const float*)d_in[0];  // (3, 8192, 64) fp32
  const float* comm  = (const float*)d_in[1];  // (16, 64) fp32
  const float* ricci = (const float*)d_in[2];  // (8192, 8192) fp32
  const float* alpha = (const float*)d_in[3];  // scalar fp32
  float* out = (float*)d_out;

  double* accum = (double*)d_ws;                         // 2 doubles @ 0
  float*  pi    = (float*)((char*)d_ws + 64);            // 512 KB
  float*  piT   = (float*)((char*)d_ws + 64 + 524288);   // 512 KB

  // ws is re-poisoned to 0xAA before every launch: zero the accumulators.
  (void)hipMemsetAsync(d_ws, 0, 64, stream);

  hipLaunchKernelGGL(k_pi,   dim3((N_NODES * N_COMM) / 256), dim3(256), 0, stream,
                     node, comm, pi, piT);
  hipLaunchKernelGGL(k_main, dim3(N_NODES / MROWS), dim3(256), 0, stream,
                     ricci, pi, piT, accum);
  hipLaunchKernelGGL(k_final, dim3(1), dim3(1), 0, stream, accum, alpha, out);
}

// Round 7
// 398.838 us; speedup vs baseline: 1.4528x; 1.0188x over previous
//
#include <hip/hip_runtime.h>
#include <math.h>

#define N_NODES 8192
#define N_COMM 16
#define DIMS 64
#define MROWS 4                      // ricci rows per block
#define JQ 4                         // j-quad per thread
#define JPI (256 * JQ)               // 1024 j's per block-iteration
#define ITERS (N_NODES / JPI)        // 8 iterations, full j-range per block
#define PITS (N_NODES + 64)          // piT row stride (padded +256B: L2 channel spread)

typedef float v4f __attribute__((ext_vector_type(4)));

// ---------------------------------------------------------------------------
// Kernel 1: pi[i,k] = softmax_k( sqrt(d_euc^2 + d_lor^2 + d_sph^2) )
// One lane per (node, k): t = i*16 + k. 16-lane softmax via shfl_xor(1,2,4,8).
// Writes pi row-major (for epilogue fold) AND transposed+padded piT (k_main).
// ---------------------------------------------------------------------------
__global__ __launch_bounds__(256) void k_pi(
    const float* __restrict__ node,   // (3, 8192, 64)
    const float* __restrict__ comm,   // (16, 64)
    float* __restrict__ pi,           // (8192, 16)
    float* __restrict__ piT)          // (16, PITS)
{
  const int t = blockIdx.x * blockDim.x + threadIdx.x;  // 0..131071
  const int i = t >> 4;
  const int k = t & 15;

  const float* xe = node + (size_t)i * DIMS;                  // Euclidean (curv 0)
  const float* xl = xe + (size_t)N_NODES * DIMS;              // Lorentz  (curv -1)
  const float* xs = xl + (size_t)N_NODES * DIMS;              // Sphere   (curv +1)
  const float* c  = comm + k * DIMS;

  float de = 0.f, il = 0.f, isp = 0.f;
#pragma unroll
  for (int d = 0; d < DIMS; d += 4) {
    v4f a  = *(const v4f*)(xe + d);
    v4f b  = *(const v4f*)(xl + d);
    v4f e  = *(const v4f*)(xs + d);
    v4f cv = *(const v4f*)(c + d);
    v4f df = a - cv;
    de  += df.x * df.x + df.y * df.y + df.z * df.z + df.w * df.w;
    il  += b.x * cv.x + b.y * cv.y + b.z * cv.z + b.w * cv.w;
    isp += e.x * cv.x + e.y * cv.y + e.z * cv.z + e.w * cv.w;
  }

  // Lorentz (kk = 1): lip = <x,c> - 2*x0*c0 ; d = arccosh(max(-lip, 1+eps))
  float lip = il - 2.0f * xl[0] * c[0];
  float arg = fmaxf(-lip, 1.0f + 1e-7f);
  float d1  = acoshf(arg);
  // Sphere: d = arccos(clip(<x,c>, -1+eps, 1-eps))
  float cs = fminf(fmaxf(isp, -1.0f + 1e-7f), 1.0f - 1e-7f);
  float d2 = acosf(cs);

  float dn = sqrtf(de + d1 * d1 + d2 * d2);

  // softmax over the 16 lanes sharing this node (lane mask bits 0..3)
  float m = dn;
#pragma unroll
  for (int off = 1; off < 16; off <<= 1) m = fmaxf(m, __shfl_xor(m, off));
  float ex = expf(dn - m);
  float ss = ex;
#pragma unroll
  for (int off = 1; off < 16; off <<= 1) ss += __shfl_xor(ss, off);

  float v = ex / ss;
  pi[t] = v;                     // coalesced
  piT[k * PITS + i] = v;         // scattered, but tiny (one store/thread)
}

// ---------------------------------------------------------------------------
// Kernel 2: single streaming pass over ricci, quad-j per thread.
// ISSUE-ORDER FIX (the round-6 lesson): vmcnt retires loads IN ISSUE ORDER.
// Prefetching next-iter ricci BEFORE this iter's piT loads meant every piT
// consume waited on the older HBM prefetch -> one full HBM latency per iter.
// New body order per iteration:
//   [16 piT dwordx4 loads]  (L2-resident, oldest)
//   [4 ricci dwordx4 prefetch for NEXT iter]  (newest -> never waited on here)
//   [256 FMAs consuming this iter's piT + the rv prefetched LAST iteration]
// Everything consumed is >= 1 iteration old; rv gets a full iter to land.
// Per-block j-phase rotation decorrelates cross-block address streams.
// NO min-waves launch bound (R4: (256,4) clamped to 64 VGPR -> 396 MB spill).
// ---------------------------------------------------------------------------
__global__ __launch_bounds__(256) void k_main(
    const float* __restrict__ ricci,   // (8192, 8192)
    const float* __restrict__ pi,      // (8192, 16) row-major
    const float* __restrict__ piT,     // (16, PITS)
    double* __restrict__ accum)        // [0]=intra_sum, [1]=inter_sum
{
  const int i0  = blockIdx.x * MROWS;       // 2048 blocks
  const int tid = threadIdx.x;
  const int ph  = blockIdx.x & (ITERS - 1); // j-phase ring
  const float* __restrict__ rbase = ricci + (size_t)i0 * N_NODES;

  float acc[MROWS][N_COMM] = {};            // 64 VGPRs
  v4f rv[2][MROWS];                         // 32 VGPRs (ping-pong)

  // prologue: ricci quads for it = 0
  {
    const int j = ph * JPI + tid * JQ;
#pragma unroll
    for (int r = 0; r < MROWS; ++r)
      rv[0][r] = *(const v4f*)(rbase + (size_t)r * N_NODES + j);
  }

#pragma unroll
  for (int it = 0; it < ITERS; ++it) {
    const int cur = it & 1, nxt = cur ^ 1;
    const int j = ((it + ph) & (ITERS - 1)) * JPI + tid * JQ;

    // ---- piT loads FIRST (oldest in vmcnt order) ----
    v4f p[N_COMM];
#pragma unroll
    for (int k = 0; k < N_COMM; ++k)
      p[k] = *(const v4f*)(piT + (size_t)k * PITS + j);

    // ---- next-iter ricci prefetch LAST among loads (newest) ----
    if (it + 1 < ITERS) {
      const int jn = ((it + 1 + ph) & (ITERS - 1)) * JPI + tid * JQ;
#pragma unroll
      for (int r = 0; r < MROWS; ++r)
        rv[nxt][r] = *(const v4f*)(rbase + (size_t)r * N_NODES + jn);
    }

    // ---- FMAs: consume piT (this iter) + rv (prefetched last iter) ----
#pragma unroll
    for (int k = 0; k < N_COMM; ++k) {
#pragma unroll
      for (int r = 0; r < MROWS; ++r) {
        v4f rr = rv[cur][r];
        acc[r][k] += rr.x * p[k].x + rr.y * p[k].y + rr.z * p[k].z + rr.w * p[k].w;
      }
    }
  }

  // per-thread epilogue: fold acc with pi rows i0..i0+3 (broadcast loads)
  float fintra = 0.f, finter = 0.f;
#pragma unroll
  for (int r = 0; r < MROWS; ++r) {
#pragma unroll
    for (int k = 0; k < N_COMM; ++k) {
      fintra += pi[(i0 + r) * N_COMM + k] * acc[r][k];
      finter += acc[r][k];
    }
  }

  // wave reduce (64 lanes) in double, then block reduce, 2 atomics/block
  double di = (double)fintra, dn = (double)finter;
#pragma unroll
  for (int off = 32; off > 0; off >>= 1) {
    di += __shfl_down(di, off);
    dn += __shfl_down(dn, off);
  }
  __shared__ double red[8];
  const int w = tid >> 6;
  if ((tid & 63) == 0) { red[w] = di; red[4 + w] = dn; }
  __syncthreads();
  if (tid == 0) {
    atomicAdd(&accum[0], red[0] + red[1] + red[2] + red[3]);
    atomicAdd(&accum[1], red[4] + red[5] + red[6] + red[7]);
  }
}

// ---------------------------------------------------------------------------
// Kernel 3: out = alpha * intra_sum/(K*N) - inter_sum/(K*K*N)
// ---------------------------------------------------------------------------
__global__ void k_final(const double* __restrict__ accum,
                        const float* __restrict__ alpha,
                        float* __restrict__ out)
{
  const double KN  = (double)N_COMM * (double)N_NODES;
  const double KKN = (double)N_COMM * (double)N_COMM * (double)N_NODES;
  out[0] = (float)((double)alpha[0] * (accum[0] / KN) - accum[1] / KKN);
}

extern "C" void kernel_launch(void* const* d_in, const int* in_sizes, int n_in,
                              void* d_out, int out_size, void* d_ws, size_t ws_size,
                              hipStream_t stream) {
  (void)in_sizes; (void)n_in; (void)out_size; (void)ws_size;

  const float* node  = (const float*)d_in[0];  // (3, 8192, 64) fp32
  const float* comm  = (const float*)d_in[1];  // (16, 64) fp32
  const float* ricci = (const float*)d_in[2];  // (8192, 8192) fp32
  const float* alpha = (const float*)d_in[3];  // scalar fp32
  float* out = (float*)d_out;

  double* accum = (double*)d_ws;                         // 2 doubles @ 0
  float*  pi    = (float*)((char*)d_ws + 64);            // 512 KB
  float*  piT   = (float*)((char*)d_ws + 64 + 524288);   // 16*PITS*4 = 528 KB

  // ws is re-poisoned to 0xAA before every launch: zero the accumulators.
  (void)hipMemsetAsync(d_ws, 0, 64, stream);

  hipLaunchKernelGGL(k_pi,   dim3((N_NODES * N_COMM) / 256), dim3(256), 0, stream,
                     node, comm, pi, piT);
  hipLaunchKernelGGL(k_main, dim3(N_NODES / MROWS), dim3(256), 0, stream,
                     ricci, pi, piT, accum);
  hipLaunchKernelGGL(k_final, dim3(1), dim3(1), 0, stream, accum, alpha, out);
}